// Round 1
// baseline (2839.109 us; speedup 1.0000x reference)
//
#include <hip/hip_runtime.h>
#include <math.h>

#define B 64
#define H 512
#define MAXN 512
#define U 512
#define MM 32
#define IN_SZ 543      // H + M - 1
#define DEC_STRIDE 544

// ---- d_out layout (floats) ----
#define PTR_OFF 0
#define PTR_SZ (B*MAXN*MM)            // 1,048,576
#define CLOSS_OFF (PTR_OFF + PTR_SZ)  // 1,048,576
#define ENC_OFF (CLOSS_OFF + 1)       // 1,048,577  (NOT 16B aligned -> scalar access to enc)
#define ENC_SZ (B*MAXN*H)             // 16,777,216
#define ADJ_OFF (ENC_OFF + ENC_SZ)    // 17,825,793

// ---- ws layout (floats) ----
#define EP_OFF 0
#define EP_SZ (B*MAXN*U)              // 16,777,216
#define HID0_OFF (EP_OFF + EP_SZ)
#define HID1_OFF (HID0_OFF + B*H)
#define W2H_OFF  (HID1_OFF + B*H)
#define COV_OFF  (W2H_OFF + B*H)
#define SC_OFF   (COV_OFF + B*MAXN)
#define DEC_OFF  (SC_OFF + B*MAXN)
#define TH_OFF   (DEC_OFF + B*DEC_STRIDE)
#define CL_OFF   (TH_OFF + B*32)
#define OFFS_OFF (CL_OFF + 64)

__device__ __forceinline__ float tanh_fast(float x){
    // tanh(x) = 1 - 2/(exp2(2*log2e*x)+1); exp2/rcp ~1ulp each
    float e = __builtin_amdgcn_exp2f(x * 2.885390081777927f);
    return 1.0f - 2.0f * __builtin_amdgcn_rcpf(e + 1.0f);
}

// ---------------- init: zero pointer/dec/cov/closs, hid0=hg, offsets ----------------
__global__ void k_init(float* __restrict__ ws, float* __restrict__ out,
                       const float* __restrict__ hg, const int* __restrict__ lengths){
    int gid = blockIdx.x*256 + threadIdx.x;
    int nth = gridDim.x*256;
    float* ptr = out + PTR_OFF;
    for (int i=gid;i<PTR_SZ;i+=nth) ptr[i]=0.f;
    float* dec = ws + DEC_OFF;
    for (int i=gid;i<B*DEC_STRIDE;i+=nth) dec[i]=0.f;
    float* cov = ws + COV_OFF;
    float* hid0 = ws + HID0_OFF;
    for (int i=gid;i<B*H;i+=nth){ cov[i]=0.f; hid0[i]=hg[i]; }
    if (gid<64) (ws+CL_OFF)[gid]=0.f;
    if (gid==0){
        int* offs=(int*)(ws+OFFS_OFF); int acc=0;
        for(int b=0;b<B;b++){ offs[b]=acc; acc+=lengths[b]; }
    }
}

// ---------------- gather enc = h[offset+n]*mask -> d_out enc region ----------------
__global__ __launch_bounds__(256) void k_gather(const float* __restrict__ h,
        const int* __restrict__ lengths, const float* __restrict__ offs_f,
        float* __restrict__ enc){
    const int* offs = (const int*)offs_f;
    int t = threadIdx.x;
    int row = blockIdx.x*2 + (t>>7);
    int c = (t&127)*4;
    int b = row >> 9, n = row & 511;
    int len = lengths[b];
    float4 v = make_float4(0.f,0.f,0.f,0.f);
    if (n < len){
        const float* p = h + (size_t)(offs[b]+n)*H + c;
        v = *(const float4*)p;  // h is aligned
    }
    float* q = enc + (size_t)row*H + c;  // enc base misaligned -> scalar stores
    q[0]=v.x; q[1]=v.y; q[2]=v.z; q[3]=v.w;
}

// ---------------- ep = enc(32768x512) @ W1^T(512x512), fp32 tiled 128x128 ----------------
__global__ __launch_bounds__(256) void k_gemm_ep(const float* __restrict__ enc,
        const float* __restrict__ W1, float* __restrict__ ep){
    __shared__ float As[16][132];
    __shared__ float Bs[16][132];
    int tid = threadIdx.x;
    int bm = blockIdx.x >> 2, bn = blockIdx.x & 3;
    int r0 = bm*128, u0 = bn*128;
    int ty = tid >> 4, tx = tid & 15;
    float acc[8][8];
#pragma unroll
    for (int i=0;i<8;i++){
#pragma unroll
        for(int j=0;j<8;j++) acc[i][j]=0.f;
    }
    for (int k0=0;k0<512;k0+=16){
        // A tile: scalar loads (enc base misaligned by 4B)
#pragma unroll
        for (int it=0; it<8; ++it){
            int idx = tid + it*256;          // 0..2047
            int row = idx >> 4, k = idx & 15;
            As[k][row] = enc[(size_t)(r0+row)*512 + k0 + k];
        }
        // B tile: W1 aligned, float4
#pragma unroll
        for (int it=0; it<2; ++it){
            int idx = tid + it*256;          // 0..511
            int nn = idx >> 2, c = idx & 3;
            float4 v = *(const float4*)&W1[(size_t)(u0+nn)*512 + k0 + c*4];
            Bs[c*4+0][nn]=v.x; Bs[c*4+1][nn]=v.y; Bs[c*4+2][nn]=v.z; Bs[c*4+3][nn]=v.w;
        }
        __syncthreads();
#pragma unroll
        for (int k=0;k<16;k++){
            float4 a0 = *(const float4*)&As[k][ty*8];
            float4 a1 = *(const float4*)&As[k][ty*8+4];
            float4 b0 = *(const float4*)&Bs[k][tx*4];
            float4 b1 = *(const float4*)&Bs[k][64+tx*4];
            float a[8]={a0.x,a0.y,a0.z,a0.w,a1.x,a1.y,a1.z,a1.w};
            float bb[8]={b0.x,b0.y,b0.z,b0.w,b1.x,b1.y,b1.z,b1.w};
#pragma unroll
            for(int im=0;im<8;im++){
#pragma unroll
                for(int jn=0;jn<8;jn++) acc[im][jn] += a[im]*bb[jn];
            }
        }
        __syncthreads();
    }
#pragma unroll
    for (int im=0;im<8;im++){
        int r = r0 + ty*8 + im;
        float4 v0 = make_float4(acc[im][0],acc[im][1],acc[im][2],acc[im][3]);
        float4 v1 = make_float4(acc[im][4],acc[im][5],acc[im][6],acc[im][7]);
        *(float4*)&ep[(size_t)r*512 + u0 + tx*4] = v0;
        *(float4*)&ep[(size_t)r*512 + u0 + 64 + tx*4] = v1;
    }
}

// ---------------- fused GRU: hid_out = GRUCell(dec_in, hid_in) ----------------
// 128 blocks, each owns 4 h-values; thread (b=tid&63, q=tid>>6) computes hid[b, h0+q]
__global__ __launch_bounds__(256) void k_gru(const float* __restrict__ dec_in,
        const float* __restrict__ hid_in, float* __restrict__ hid_out,
        const float* __restrict__ w_ih, const float* __restrict__ w_hh,
        const float* __restrict__ b_ih, const float* __restrict__ b_hh){
    __shared__ float As[64][36];
    __shared__ float Ws[12][36];
    int tid=threadIdx.x; int b=tid&63; int q=tid>>6;
    int h0=blockIdx.x*4;
    float aI0=0,aI1=0,aI2=0,aH0=0,aH1=0,aH2=0;
    // phase 1: gi over K=543 (dec_in stride 544, aligned)
    for (int k0=0;k0<IN_SZ;k0+=32){
        for (int it=0;it<2;it++){
            int idx=tid+it*256; int row=idx>>3, c=idx&7; int k=k0+c*4;
            float4 v=make_float4(0.f,0.f,0.f,0.f);
            const float* p=&dec_in[row*DEC_STRIDE+k];
            if (k+3 < IN_SZ) v=*(const float4*)p;
            else { if(k<IN_SZ)v.x=p[0]; if(k+1<IN_SZ)v.y=p[1]; if(k+2<IN_SZ)v.z=p[2]; }
            *(float4*)&As[row][c*4]=v;
        }
        if (tid<96){
            int rr=tid>>3,c=tid&7; int g=rr>>2,qq=rr&3;
            int j=h0+qq+512*g; int k=k0+c*4;
            float4 v=make_float4(0.f,0.f,0.f,0.f);
            const float* p=&w_ih[(size_t)j*IN_SZ+k];     // stride 543: misaligned -> scalar
            if(k<IN_SZ)v.x=p[0]; if(k+1<IN_SZ)v.y=p[1];
            if(k+2<IN_SZ)v.z=p[2]; if(k+3<IN_SZ)v.w=p[3];
            *(float4*)&Ws[rr][c*4]=v;
        }
        __syncthreads();
#pragma unroll
        for (int kk=0;kk<32;kk+=4){
            float4 a=*(const float4*)&As[b][kk];
            float4 w0=*(const float4*)&Ws[q][kk];
            float4 w1=*(const float4*)&Ws[4+q][kk];
            float4 w2=*(const float4*)&Ws[8+q][kk];
            aI0 += a.x*w0.x + a.y*w0.y + a.z*w0.z + a.w*w0.w;
            aI1 += a.x*w1.x + a.y*w1.y + a.z*w1.z + a.w*w1.w;
            aI2 += a.x*w2.x + a.y*w2.y + a.z*w2.z + a.w*w2.w;
        }
        __syncthreads();
    }
    // phase 2: gh over K=512 (hid stride 512, aligned)
    for (int k0=0;k0<512;k0+=32){
        for (int it=0;it<2;it++){
            int idx=tid+it*256; int row=idx>>3,c=idx&7; int k=k0+c*4;
            *(float4*)&As[row][c*4] = *(const float4*)&hid_in[row*512+k];
        }
        if (tid<96){
            int rr=tid>>3,c=tid&7; int g=rr>>2,qq=rr&3;
            int j=h0+qq+512*g; int k=k0+c*4;
            *(float4*)&Ws[rr][c*4] = *(const float4*)&w_hh[(size_t)j*512+k];
        }
        __syncthreads();
#pragma unroll
        for (int kk=0;kk<32;kk+=4){
            float4 a=*(const float4*)&As[b][kk];
            float4 w0=*(const float4*)&Ws[q][kk];
            float4 w1=*(const float4*)&Ws[4+q][kk];
            float4 w2=*(const float4*)&Ws[8+q][kk];
            aH0 += a.x*w0.x + a.y*w0.y + a.z*w0.z + a.w*w0.w;
            aH1 += a.x*w1.x + a.y*w1.y + a.z*w1.z + a.w*w1.w;
            aH2 += a.x*w2.x + a.y*w2.y + a.z*w2.z + a.w*w2.w;
        }
        __syncthreads();
    }
    int h=h0+q;
    float gi0=aI0+b_ih[h], gi1=aI1+b_ih[h+512], gi2=aI2+b_ih[h+1024];
    float gh0=aH0+b_hh[h], gh1=aH1+b_hh[h+512], gh2=aH2+b_hh[h+1024];
    float r=1.f/(1.f+expf(-(gi0+gh0)));
    float z=1.f/(1.f+expf(-(gi1+gh1)));
    float nn=tanhf(gi2 + r*gh2);
    float hp=hid_in[b*512+h];
    hid_out[b*512+h]=(1.f-z)*nn+z*hp;
}

// ---------------- w2h = hid @ W2^T (blocks 0..127) ; theta (blocks 128..135) ----------------
__global__ __launch_bounds__(256) void k_w2h_theta(const float* __restrict__ hid,
        const float* __restrict__ W2, const float* __restrict__ Wf, const float* __restrict__ bf,
        float* __restrict__ w2h, float* __restrict__ theta, float* __restrict__ adj, int step){
    __shared__ float As[64][36];
    __shared__ float Ws[4][36];
    int tid=threadIdx.x; int b=tid&63; int q=tid>>6;
    bool isTheta = blockIdx.x >= 128;
    int r0 = isTheta ? (int)(blockIdx.x-128)*4 : (int)blockIdx.x*4;
    const float* W = isTheta ? Wf : W2;
    int row = r0 + q;
    float acc=0.f;
    for (int k0=0;k0<512;k0+=32){
        for (int it=0;it<2;it++){
            int idx=tid+it*256; int rw=idx>>3,c=idx&7; int k=k0+c*4;
            *(float4*)&As[rw][c*4]=*(const float4*)&hid[rw*512+k];
        }
        if (tid<32){
            int rr=tid>>3,c=tid&7; int j=r0+rr; int k=k0+c*4;
            float4 v=make_float4(0.f,0.f,0.f,0.f);
            if (!isTheta || j<31) v=*(const float4*)&W[(size_t)j*512+k];
            *(float4*)&Ws[rr][c*4]=v;
        }
        __syncthreads();
#pragma unroll
        for(int kk=0;kk<32;kk+=4){
            float4 a=*(const float4*)&As[b][kk];
            float4 w=*(const float4*)&Ws[q][kk];
            acc += a.x*w.x+a.y*w.y+a.z*w.z+a.w*w.w;
        }
        __syncthreads();
    }
    if (!isTheta){
        w2h[b*512 + row] = acc;
    } else if (row < 31){
        float th = 1.f/(1.f+expf(-(acc + bf[row])));
        th = (row < step) ? th : 0.f;
        theta[b*32+row]=th;
        adj[b*992 + row*32 + step]=th;
    }
}

// ---------------- scores[b,n] = sum_u tanh(ep + w2h + cov*wc) * v ----------------
__global__ __launch_bounds__(256) void k_scores(const float* __restrict__ ep,
        const float* __restrict__ w2h, const float* __restrict__ cov,
        const float* __restrict__ wc, const float* __restrict__ v,
        const int* __restrict__ lengths, float* __restrict__ scores){
    __shared__ float sW[512], sV[512], sC[512];
    int b = blockIdx.x >> 7, chunk = blockIdx.x & 127;
    int n0 = chunk*4;
    int len = lengths[b];
    if (n0 >= len) return;   // block-uniform
    int tid=threadIdx.x;
    for (int idx=tid; idx<384; idx+=256){
        int which = idx>>7, c = (idx&127)*4;
        float4 val;
        if (which==0) val=*(const float4*)&w2h[b*512+c];
        else if (which==1) val=*(const float4*)&v[c];
        else val=*(const float4*)&wc[c];
        float* dst = (which==0)?sW:((which==1)?sV:sC);
        *(float4*)&dst[c]=val;
    }
    __syncthreads();
    int wave=tid>>6, lane=tid&63;
    int n = n0 + wave;
    float cb = cov[b*512+n];
    const float4* row = (const float4*)&ep[(size_t)(b*512+n)*512];
    float acc=0.f;
#pragma unroll
    for (int kk=0;kk<2;kk++){
        int u4 = kk*64 + lane;
        float4 e=row[u4];
        float4 w=*(const float4*)&sW[u4*4];
        float4 cc=*(const float4*)&sC[u4*4];
        float4 vv=*(const float4*)&sV[u4*4];
        acc += tanh_fast(e.x + w.x + cb*cc.x)*vv.x;
        acc += tanh_fast(e.y + w.y + cb*cc.y)*vv.y;
        acc += tanh_fast(e.z + w.z + cb*cc.z)*vv.z;
        acc += tanh_fast(e.w + w.w + cb*cc.w)*vv.w;
    }
#pragma unroll
    for (int m=1;m<64;m<<=1) acc += __shfl_xor(acc, m, 64);
    if (lane==0) scores[b*512+n]=acc;
}

// ---------------- per-b: softmax, coverage, closs, argmax, pointer, dec_in ----------------
__global__ __launch_bounds__(512) void k_soft(const float* __restrict__ scores,
        const float* __restrict__ gum, const int* __restrict__ lengths,
        const float* __restrict__ enc, const float* __restrict__ theta,
        float* __restrict__ cov, float* __restrict__ dec_in, float* __restrict__ closs_b,
        float* __restrict__ pointer, int step){
    __shared__ float red[512];
    __shared__ int redi[512];
    int b=blockIdx.x, n=threadIdx.x;
    int len=lengths[b];
    float s = (n<len)? scores[b*512+n] : -1e30f;
    red[n]=s; __syncthreads();
    for(int o=256;o>=1;o>>=1){ if(n<o) red[n]=fmaxf(red[n],red[n+o]); __syncthreads(); }
    float mx=red[0]; __syncthreads();
    float e=(n<len)? expf(s-mx):0.f;
    red[n]=e; __syncthreads();
    for(int o=256;o>=1;o>>=1){ if(n<o) red[n]+=red[n+o]; __syncthreads(); }
    float Z=red[0]; __syncthreads();
    float att=e/Z;
    float c=cov[b*512+n];
    float cl=fminf(att,c);
    red[n]=cl; __syncthreads();
    for(int o=256;o>=1;o>>=1){ if(n<o) red[n]+=red[n+o]; __syncthreads(); }
    if(n==0) closs_b[b]+=red[0];
    __syncthreads();
    cov[b*512+n]=c+att;
    float lg=logf(att+1e-12f)+gum[((size_t)step*64+b)*512+n];
    red[n]=lg; redi[n]=n; __syncthreads();
    for(int o=256;o>=1;o>>=1){
        if(n<o){ if(red[n+o]>red[n]){red[n]=red[n+o];redi[n]=redi[n+o];} }
        __syncthreads();
    }
    int ns=redi[0];
    if(n==0) pointer[b*16384 + ns*32 + step]=1.f;
    dec_in[b*DEC_STRIDE+n]=enc[((size_t)b*512+ns)*512+n];
    if(n<31) dec_in[b*DEC_STRIDE+512+n]=theta[b*32+n];
}

__global__ void k_final(const float* __restrict__ closs_b, float* __restrict__ out){
    if (threadIdx.x==0 && blockIdx.x==0){
        float s=0.f;
        for(int b=0;b<B;b++) s+=closs_b[b];
        out[CLOSS_OFF]=s/64.f;
    }
}

extern "C" void kernel_launch(void* const* d_in, const int* in_sizes, int n_in,
                              void* d_out, int out_size, void* d_ws, size_t ws_size,
                              hipStream_t stream){
    const float* h      = (const float*)d_in[0];
    const float* hg     = (const float*)d_in[1];
    const int*   lengths= (const int*)  d_in[2];
    const float* gumbel = (const float*)d_in[3];
    const float* W1     = (const float*)d_in[4];
    const float* W2     = (const float*)d_in[5];
    const float* wc     = (const float*)d_in[6];
    const float* v      = (const float*)d_in[7];
    const float* w_ih   = (const float*)d_in[8];
    const float* w_hh   = (const float*)d_in[9];
    const float* b_ih   = (const float*)d_in[10];
    const float* b_hh   = (const float*)d_in[11];
    const float* Wf     = (const float*)d_in[12];
    const float* bf     = (const float*)d_in[13];
    float* out = (float*)d_out;
    float* ws  = (float*)d_ws;
    float* enc = out + ENC_OFF;
    float* adj = out + ADJ_OFF;
    float* pointer = out + PTR_OFF;
    float* ep   = ws + EP_OFF;
    float* hidA = ws + HID0_OFF;
    float* hidB = ws + HID1_OFF;
    float* w2h  = ws + W2H_OFF;
    float* cov  = ws + COV_OFF;
    float* sc   = ws + SC_OFF;
    float* dec  = ws + DEC_OFF;
    float* th   = ws + TH_OFF;
    float* clb  = ws + CL_OFF;
    float* offs = ws + OFFS_OFF;

    hipLaunchKernelGGL(k_init,   dim3(512),  dim3(256), 0, stream, ws, out, hg, lengths);
    hipLaunchKernelGGL(k_gather, dim3(16384),dim3(256), 0, stream, h, lengths, offs, enc);
    hipLaunchKernelGGL(k_gemm_ep,dim3(1024), dim3(256), 0, stream, enc, W1, ep);
    for (int i=0;i<MM;i++){
        const float* hin = (i&1)? hidB : hidA;
        float*       hout= (i&1)? hidA : hidB;
        hipLaunchKernelGGL(k_gru,       dim3(128), dim3(256), 0, stream,
                           dec, hin, hout, w_ih, w_hh, b_ih, b_hh);
        hipLaunchKernelGGL(k_w2h_theta, dim3(136), dim3(256), 0, stream,
                           hout, W2, Wf, bf, w2h, th, adj, i);
        hipLaunchKernelGGL(k_scores,    dim3(8192),dim3(256), 0, stream,
                           ep, w2h, cov, wc, v, lengths, sc);
        hipLaunchKernelGGL(k_soft,      dim3(64),  dim3(512), 0, stream,
                           sc, gumbel, lengths, enc, th, cov, dec, clb, pointer, i);
    }
    hipLaunchKernelGGL(k_final, dim3(1), dim3(64), 0, stream, clb, out);
}